// Round 4
// baseline (642.479 us; speedup 1.0000x reference)
//
#include <hip/hip_runtime.h>
#include <hip/hip_cooperative_groups.h>

namespace cg = cooperative_groups;

// Wave forward: 16 channels, 208x208 window/channel, 48 steps, ONE cooperative
// persistent kernel (6 phases x 8 substeps, grid.sync at phase boundaries).
// Register-blocked 4x4 cells/thread; LDS ping-pong holds current level only;
// only ring threads touch global at boundaries. Support-cone tile skipping.

#define GN     512
#define NMASK  511
#define NCH    16
#define NT     48
#define NM     128
#define WW     208            // window size
#define WOFF   103            // source offset inside window
#define TI     52             // tile interior
#define TS     8              // substeps per phase
#define NPHASE 6
#define HALO   16             // 2*TS
#define LT     84             // TI + 2*HALO
#define LT2    (LT*LT)
#define WCELLS (WW*WW)        // 43264
#define NTH    448            // 7 waves
#define NACT   441            // 21x21 threads x 4x4 cells = 84^2

__global__ void coef_kernel(const float* __restrict__ x,
                            const int* __restrict__ trans,
                            float* __restrict__ coefw) {
    int idx = blockIdx.x * 256 + threadIdx.x;
    if (idx >= NCH * WCELLS) return;
    int r  = idx / WCELLS;
    int c  = idx - r * WCELLS;
    int li = c / WW, lj = c - (c / WW) * WW;
    int tr = trans[r];
    int ox = (tr >> 9) - WOFF, oy = (tr & NMASK) - WOFF;
    int gi = (ox + li) & NMASK, gj = (oy + lj) & NMASK;
    float xp;
    if (gi < 55 || gi >= 457 || gj < 55 || gj >= 457)
        xp = 1e-6f;                                   // ABC pad
    else if (gi >= 128 && gi < 384 && gj >= 128 && gj < 384)
        xp = x[(gi - 128) * 256 + (gj - 128)];
    else
        xp = 1.5f;                                    // bg pad
    float t = 0.2f * xp;
    coefw[idx] = t * t;
}

__device__ __forceinline__ float4 ld4(const float* p) { return *(const float4*)p; }
__device__ __forceinline__ void st4(float* p, float4 v) { *(float4*)p = v; }

__global__ __launch_bounds__(NTH, 1)
void persist_kernel(const float* __restrict__ coefw,
                    const int* __restrict__ trans,
                    const int* __restrict__ meas,
                    const float* __restrict__ src,
                    float* __restrict__ GA0, float* __restrict__ GA1,
                    float* __restrict__ GB0, float* __restrict__ GB1,
                    float* __restrict__ out)
{
    cg::grid_group grid = cg::this_grid();
    __shared__ float lds0[LT2];
    __shared__ float lds1[LT2];
    const int tid  = threadIdx.x;
    const int b    = blockIdx.x;
    const int r    = b >> 4;
    const int tile = b & 15;
    const int ri0  = (tile >> 2) * TI - HALO;
    const int rj0  = (tile &  3) * TI - HALO;
    const float* cw = coefw + r * WCELLS;

    const bool active = tid < NACT;
    const int ty = tid / 21, tx = tid - 21 * (tid / 21);
    const int li0 = 4 * ty, lj0 = 4 * tx;
    const bool inner = active && tx >= 4 && tx <= 16 && ty >= 4 && ty <= 16;

    // zero the stage buffer (initial field is zero)
    for (int q = tid; q < LT2 / 4; q += NTH)
        st4(&lds0[q * 4], make_float4(0.f, 0.f, 0.f, 0.f));

    // per-thread state: C = f_{s-1}, P = f_{s-2}, K = coef
    float C[16], P[16], K[16];
    #pragma unroll
    for (int i = 0; i < 16; ++i) { C[i] = 0.f; P[i] = 0.f; K[i] = 0.f; }

    int offT2 = 0, offT1 = 0, offB1 = 0, offB2 = 0;
    int offL[4] = {0,0,0,0}, offR[4] = {0,0,0,0}, offC[4] = {0,0,0,0};
    unsigned smask = 0;
    if (active) {
        #pragma unroll
        for (int rr = 0; rr < 4; ++rr) {
            int wr = ri0 + li0 + rr, wc = rj0 + lj0;
            float4 vk = make_float4(0,0,0,0);
            if ((unsigned)wr < WW && (unsigned)wc < WW)
                vk = ld4(cw + wr * WW + wc);
            K[rr*4+0]=vk.x; K[rr*4+1]=vk.y; K[rr*4+2]=vk.z; K[rr*4+3]=vk.w;
        }
        int rT2 = li0 - 2 < 0 ? 0 : li0 - 2;
        int rT1 = li0 - 1 < 0 ? 0 : li0 - 1;
        int rB1 = li0 + 4 > LT - 1 ? LT - 1 : li0 + 4;
        int rB2 = li0 + 5 > LT - 1 ? LT - 1 : li0 + 5;
        offT2 = rT2 * LT + lj0;  offT1 = rT1 * LT + lj0;
        offB1 = rB1 * LT + lj0;  offB2 = rB2 * LT + lj0;
        #pragma unroll
        for (int rr = 0; rr < 4; ++rr) {
            int base = (li0 + rr) * LT + lj0;
            offC[rr] = base;
            int ol = base - 4;  if (ol < 0) ol = 0;
            int orr = base + 4; if (orr > LT2 - 4) orr = LT2 - 4;
            offL[rr] = ol; offR[rr] = orr;
        }
        int si = (WOFF - ri0) - li0, sj = (WOFF - rj0) - lj0;
        if (si >= 0 && si < 4 && sj >= 0 && sj < 4) smask = 1u << (si * 4 + sj);
    }

    // measurement ownership (fixed across phases)
    bool mvalid = false; int mlds = 0; float* mout = nullptr;
    {
        int tr = trans[r];
        int ox = (tr >> 9) - WOFF, oy = (tr & NMASK) - WOFF;
        if (tid < NM) {
            int mc = meas[tid];
            int mi = ((mc >> 9)    - ox) & NMASK;
            int mj = ((mc & NMASK) - oy) & NMASK;
            int li = mi - ri0, lj = mj - rj0;
            mvalid = (li >= HALO && li < HALO + TI && lj >= HALO && lj < HALO + TI);
            mlds = li * LT + lj;
            mout = out + (size_t)(r * NM + tid) * NT;
        }
    }

    // support-cone distance: L-inf distance from tile's 84^2 region to source
    int lsi = WOFF - ri0, lsj = WOFF - rj0;
    int di = lsi < 0 ? -lsi : (lsi > LT - 1 ? lsi - (LT - 1) : 0);
    int dj = lsj < 0 ? -lsj : (lsj > LT - 1 ? lsj - (LT - 1) : 0);
    const int sdist = di > dj ? di : dj;

    __syncthreads();

    auto step1 = [&](float (&A)[16], float (&B)[16],
                     const float* rd, float* wb, float sval, int jj) {
        if (active) {
            float t2[4], t1[4], b1a[4], b2a[4];
            float4 v;
            v = ld4(rd + offT2); t2[0]=v.x;  t2[1]=v.y;  t2[2]=v.z;  t2[3]=v.w;
            v = ld4(rd + offT1); t1[0]=v.x;  t1[1]=v.y;  t1[2]=v.z;  t1[3]=v.w;
            v = ld4(rd + offB1); b1a[0]=v.x; b1a[1]=v.y; b1a[2]=v.z; b1a[3]=v.w;
            v = ld4(rd + offB2); b2a[0]=v.x; b2a[1]=v.y; b2a[2]=v.z; b2a[3]=v.w;
            float Lw[4][4], Rw[4][4];
            #pragma unroll
            for (int rr = 0; rr < 4; ++rr) {
                v = ld4(rd + offL[rr]); Lw[rr][0]=v.x; Lw[rr][1]=v.y; Lw[rr][2]=v.z; Lw[rr][3]=v.w;
                v = ld4(rd + offR[rr]); Rw[rr][0]=v.x; Rw[rr][1]=v.y; Rw[rr][2]=v.z; Rw[rr][3]=v.w;
            }
            #pragma unroll
            for (int rr = 0; rr < 4; ++rr) {
                float w[12];
                w[0]=Lw[rr][0]; w[1]=Lw[rr][1]; w[2]=Lw[rr][2];  w[3]=Lw[rr][3];
                w[4]=B[rr*4+0]; w[5]=B[rr*4+1]; w[6]=B[rr*4+2];  w[7]=B[rr*4+3];
                w[8]=Rw[rr][0]; w[9]=Rw[rr][1]; w[10]=Rw[rr][2]; w[11]=Rw[rr][3];
                #pragma unroll
                for (int cc = 0; cc < 4; ++cc) {
                    float vm2 = (rr == 0) ? t2[cc]  : (rr == 1) ? t1[cc]  : B[(rr-2)*4+cc];
                    float vm1 = (rr == 0) ? t1[cc]  : B[(rr-1)*4+cc];
                    float vp1 = (rr == 3) ? b1a[cc] : B[(rr+1)*4+cc];
                    float vp2 = (rr == 3) ? b2a[cc] : (rr == 2) ? b1a[cc] : B[(rr+2)*4+cc];
                    float c0  = w[4+cc];
                    float lap = (16.f * (w[3+cc] + w[5+cc] + vm1 + vp1)
                                 - (w[2+cc] + w[6+cc] + vm2 + vp2)
                                 - 60.f * c0) * (1.f / 12.f);
                    float pn = 2.f * c0 - A[rr*4+cc] + K[rr*4+cc] * lap;
                    if (smask & (1u << (rr*4+cc))) pn += sval;
                    A[rr*4+cc] = pn;
                }
                st4(wb + offC[rr],
                    make_float4(A[rr*4+0], A[rr*4+1], A[rr*4+2], A[rr*4+3]));
            }
        }
        __syncthreads();
        if (mvalid) mout[jj] = wb[mlds];
    };

    for (int ph = 0; ph < NPHASE; ++ph) {
        const int J = ph * TS;
        // support cone: f_j support radius <= 2*j; this phase reaches j=J+TS.
        const bool live = sdist <= 2 * (J + TS) + 4;
        if (live) {
            float sv[TS];
            #pragma unroll
            for (int s = 0; s < TS; ++s) sv[s] = 0.09f * src[J + s];
            step1(P, C, lds0, lds1, sv[0], J + 0);
            step1(C, P, lds1, lds0, sv[1], J + 1);
            step1(P, C, lds0, lds1, sv[2], J + 2);
            step1(C, P, lds1, lds0, sv[3], J + 3);
            step1(P, C, lds0, lds1, sv[4], J + 4);
            step1(C, P, lds1, lds0, sv[5], J + 5);
            step1(P, C, lds0, lds1, sv[6], J + 6);
            step1(C, P, lds1, lds0, sv[7], J + 7);
            // C = f_{J+7}, P = f_{J+6}; lds0 = f_{J+7} (valid on [16,68)^2)
        }
        if (ph < NPHASE - 1) {
            float* W0 = (ph & 1) ? GB0 : GA0;
            float* W1 = (ph & 1) ? GB1 : GA1;
            if (inner) {   // interior partition of both levels -> global
                float* c0p = W0 + r * WCELLS;
                float* c1p = W1 + r * WCELLS;
                #pragma unroll
                for (int rr = 0; rr < 4; ++rr) {
                    int wi = (ri0 + li0 + rr) * WW + (rj0 + lj0);
                    st4(c1p + wi, make_float4(C[rr*4+0], C[rr*4+1], C[rr*4+2], C[rr*4+3]));
                    st4(c0p + wi, make_float4(P[rr*4+0], P[rr*4+1], P[rr*4+2], P[rr*4+3]));
                }
            }
            __threadfence();
            grid.sync();
            __threadfence();
            if (active && !inner) {   // ring threads: reload regs + restage LDS
                const float* c0p = W0 + r * WCELLS;
                const float* c1p = W1 + r * WCELLS;
                #pragma unroll
                for (int rr = 0; rr < 4; ++rr) {
                    int wr = ri0 + li0 + rr, wc = rj0 + lj0;
                    float4 vc = make_float4(0,0,0,0), vp = vc;
                    if ((unsigned)wr < WW && (unsigned)wc < WW) {
                        vc = ld4(c1p + wr * WW + wc);
                        vp = ld4(c0p + wr * WW + wc);
                    }
                    C[rr*4+0]=vc.x; C[rr*4+1]=vc.y; C[rr*4+2]=vc.z; C[rr*4+3]=vc.w;
                    P[rr*4+0]=vp.x; P[rr*4+1]=vp.y; P[rr*4+2]=vp.z; P[rr*4+3]=vp.w;
                    st4(&lds0[offC[rr]], vc);
                }
            }
            __syncthreads();   // lds0 fully = f_{J+7} before next phase
        }
    }
}

extern "C" void kernel_launch(void* const* d_in, const int* in_sizes, int n_in,
                              void* d_out, int out_size, void* d_ws, size_t ws_size,
                              hipStream_t stream)
{
    const float* x     = (const float*)d_in[0];
    const float* src   = (const float*)d_in[1];
    const int*   meas  = (const int*)d_in[2];
    const int*   trans = (const int*)d_in[3];
    float* outp = (float*)d_out;

    float* coefw = (float*)d_ws;
    float* GA0 = coefw + (size_t)NCH * WCELLS;
    float* GA1 = GA0 + (size_t)NCH * WCELLS;
    float* GB0 = GA1 + (size_t)NCH * WCELLS;
    float* GB1 = GB0 + (size_t)NCH * WCELLS;

    hipMemsetAsync(outp, 0, (size_t)out_size * sizeof(float), stream);
    coef_kernel<<<(NCH * WCELLS + 255) / 256, 256, 0, stream>>>(x, trans, coefw);

    void* args[] = { (void*)&coefw, (void*)&trans, (void*)&meas, (void*)&src,
                     (void*)&GA0, (void*)&GA1, (void*)&GB0, (void*)&GB1,
                     (void*)&outp };
    hipLaunchCooperativeKernel((void*)persist_kernel, dim3(256), dim3(NTH),
                               args, 0, stream);
}

// Round 5
// 170.504 us; speedup vs baseline: 3.7681x; 3.7681x over previous
//
#include <hip/hip_runtime.h>

// Wave forward: 16 channels, 208x208 window/channel, 48 steps, ONE persistent
// (non-cooperative) kernel. 6 phases x 8 substeps; at phase boundaries blocks
// sync only with their 3x3 tile neighborhood via agent-scope flags + fences.
// Register-blocked 4x4 cells/thread; LDS ping-pong (padded stride 88) holds
// the current level; only ring threads touch global at boundaries.

#define GN     512
#define NMASK  511
#define NCH    16
#define NT     48
#define NM     128
#define WW     208            // window size
#define WOFF   103            // source offset inside window
#define TI     52             // tile interior
#define TS     8              // substeps per phase
#define NPHASE 6
#define HALO   16             // 2*TS
#define LT     84             // logical tile width (TI + 2*HALO)
#define LTS    88             // padded LDS row stride (bank-conflict fix)
#define LDSE   (LTS*LT)
#define WCELLS (WW*WW)        // 43264
#define NTH    448            // 7 waves
#define NACT   441            // 21x21 threads x 4x4 cells = 84^2
#define NBLK   256

__device__ __forceinline__ float4 ld4(const float* p) { return *(const float4*)p; }
__device__ __forceinline__ void st4(float* p, float4 v) { *(float4*)p = v; }

__device__ __forceinline__ float kcoef(const float* __restrict__ x, int gi, int gj) {
    float xp;
    if (gi < 55 || gi >= 457 || gj < 55 || gj >= 457)
        xp = 1e-6f;                                   // ABC pad
    else if (gi >= 128 && gi < 384 && gj >= 128 && gj < 384)
        xp = x[(gi - 128) * 256 + (gj - 128)];
    else
        xp = 1.5f;                                    // bg pad
    float t = 0.2f * xp;
    return t * t;
}

__global__ __launch_bounds__(NTH, 1)
void persist_kernel(const float* __restrict__ x,
                    const float* __restrict__ src,
                    const int* __restrict__ meas,
                    const int* __restrict__ trans,
                    int* __restrict__ flags,
                    float* __restrict__ GA0, float* __restrict__ GA1,
                    float* __restrict__ GB0, float* __restrict__ GB1,
                    float* __restrict__ out)
{
    __shared__ float lds0[LDSE];
    __shared__ float lds1[LDSE];
    const int tid  = threadIdx.x;
    const int b    = blockIdx.x;
    const int r    = b >> 4;
    const int tile = b & 15;
    const int ri0  = (tile >> 2) * TI - HALO;
    const int rj0  = (tile &  3) * TI - HALO;

    const bool active = tid < NACT;
    const int ty = tid / 21, tx = tid - 21 * (tid / 21);
    const int li0 = 4 * ty, lj0 = 4 * tx;
    const bool inner = active && tx >= 4 && tx <= 16 && ty >= 4 && ty <= 16;

    // zero stage buffer (initial field is zero; padded tails too)
    for (int q = tid; q < LDSE / 4; q += NTH)
        st4(&lds0[q * 4], make_float4(0.f, 0.f, 0.f, 0.f));

    const int trv = trans[r];
    const int ox = (trv >> 9) - WOFF, oy = (trv & NMASK) - WOFF;

    // per-thread state: C = f_{s-1}, P = f_{s-2}, K = coef
    float C[16], P[16], K[16];
    #pragma unroll
    for (int i = 0; i < 16; ++i) { C[i] = 0.f; P[i] = 0.f; K[i] = 0.f; }

    int offT2 = 0, offT1 = 0, offB1 = 0, offB2 = 0;
    int offL[4] = {0,0,0,0}, offR[4] = {0,0,0,0}, offC[4] = {0,0,0,0};
    unsigned smask = 0;
    if (active) {
        #pragma unroll
        for (int rr = 0; rr < 4; ++rr) {
            int wr = ri0 + li0 + rr;
            #pragma unroll
            for (int cc = 0; cc < 4; ++cc) {
                int wc = rj0 + lj0 + cc;
                K[rr*4+cc] = kcoef(x, (ox + wr) & NMASK, (oy + wc) & NMASK);
            }
        }
        int rT2 = li0 - 2 < 0 ? 0 : li0 - 2;
        int rT1 = li0 - 1 < 0 ? 0 : li0 - 1;
        int rB1 = li0 + 4 > LT - 1 ? LT - 1 : li0 + 4;
        int rB2 = li0 + 5 > LT - 1 ? LT - 1 : li0 + 5;
        offT2 = rT2 * LTS + lj0;  offT1 = rT1 * LTS + lj0;
        offB1 = rB1 * LTS + lj0;  offB2 = rB2 * LTS + lj0;
        #pragma unroll
        for (int rr = 0; rr < 4; ++rr) {
            int base = (li0 + rr) * LTS + lj0;
            offC[rr] = base;
            int ol = base - 4;  if (ol < 0) ol = 0;
            int orr = base + 4; if (orr > LDSE - 4) orr = LDSE - 4;
            offL[rr] = ol; offR[rr] = orr;
        }
        int si = (WOFF - ri0) - li0, sj = (WOFF - rj0) - lj0;
        if (si >= 0 && si < 4 && sj >= 0 && sj < 4) smask = 1u << (si * 4 + sj);
    }

    // measurement ownership (fixed across phases)
    bool mvalid = false; int mlds = 0; float* mout = nullptr;
    if (tid < NM) {
        int mc = meas[tid];
        int mi = ((mc >> 9)    - ox) & NMASK;
        int mj = ((mc & NMASK) - oy) & NMASK;
        int li = mi - ri0, lj = mj - rj0;
        mvalid = (li >= HALO && li < HALO + TI && lj >= HALO && lj < HALO + TI);
        mlds = li * LTS + lj;
        mout = out + (size_t)(r * NM + tid) * NT;
    }

    // support-cone distance from tile's 84^2 region to the source
    int lsi = WOFF - ri0, lsj = WOFF - rj0;
    int di = lsi < 0 ? -lsi : (lsi > LT - 1 ? lsi - (LT - 1) : 0);
    int dj = lsj < 0 ? -lsj : (lsj > LT - 1 ? lsj - (LT - 1) : 0);
    const int sdist = di > dj ? di : dj;

    __syncthreads();

    auto step1 = [&](float (&A)[16], float (&B)[16],
                     const float* rd, float* wb, float sval, int jj) {
        if (active) {
            float t2[4], t1[4], b1a[4], b2a[4];
            float4 v;
            v = ld4(rd + offT2); t2[0]=v.x;  t2[1]=v.y;  t2[2]=v.z;  t2[3]=v.w;
            v = ld4(rd + offT1); t1[0]=v.x;  t1[1]=v.y;  t1[2]=v.z;  t1[3]=v.w;
            v = ld4(rd + offB1); b1a[0]=v.x; b1a[1]=v.y; b1a[2]=v.z; b1a[3]=v.w;
            v = ld4(rd + offB2); b2a[0]=v.x; b2a[1]=v.y; b2a[2]=v.z; b2a[3]=v.w;
            float Lw[4][4], Rw[4][4];
            #pragma unroll
            for (int rr = 0; rr < 4; ++rr) {
                v = ld4(rd + offL[rr]); Lw[rr][0]=v.x; Lw[rr][1]=v.y; Lw[rr][2]=v.z; Lw[rr][3]=v.w;
                v = ld4(rd + offR[rr]); Rw[rr][0]=v.x; Rw[rr][1]=v.y; Rw[rr][2]=v.z; Rw[rr][3]=v.w;
            }
            #pragma unroll
            for (int rr = 0; rr < 4; ++rr) {
                float w[12];
                w[0]=Lw[rr][0]; w[1]=Lw[rr][1]; w[2]=Lw[rr][2];  w[3]=Lw[rr][3];
                w[4]=B[rr*4+0]; w[5]=B[rr*4+1]; w[6]=B[rr*4+2];  w[7]=B[rr*4+3];
                w[8]=Rw[rr][0]; w[9]=Rw[rr][1]; w[10]=Rw[rr][2]; w[11]=Rw[rr][3];
                #pragma unroll
                for (int cc = 0; cc < 4; ++cc) {
                    float vm2 = (rr == 0) ? t2[cc]  : (rr == 1) ? t1[cc]  : B[(rr-2)*4+cc];
                    float vm1 = (rr == 0) ? t1[cc]  : B[(rr-1)*4+cc];
                    float vp1 = (rr == 3) ? b1a[cc] : B[(rr+1)*4+cc];
                    float vp2 = (rr == 3) ? b2a[cc] : (rr == 2) ? b1a[cc] : B[(rr+2)*4+cc];
                    float c0  = w[4+cc];
                    float lap = (16.f * (w[3+cc] + w[5+cc] + vm1 + vp1)
                                 - (w[2+cc] + w[6+cc] + vm2 + vp2)
                                 - 60.f * c0) * (1.f / 12.f);
                    float pn = 2.f * c0 - A[rr*4+cc] + K[rr*4+cc] * lap;
                    if (smask & (1u << (rr*4+cc))) pn += sval;
                    A[rr*4+cc] = pn;
                }
                st4(wb + offC[rr],
                    make_float4(A[rr*4+0], A[rr*4+1], A[rr*4+2], A[rr*4+3]));
            }
        }
        __syncthreads();
        if (mvalid) mout[jj] = wb[mlds];
    };

    for (int ph = 0; ph < NPHASE; ++ph) {
        const int J = ph * TS;
        const bool live = sdist <= 2 * (J + TS) + 4;   // cone: radius 2/step
        if (live) {
            float sv[TS];
            #pragma unroll
            for (int s = 0; s < TS; ++s) sv[s] = 0.09f * src[J + s];
            step1(P, C, lds0, lds1, sv[0], J + 0);
            step1(C, P, lds1, lds0, sv[1], J + 1);
            step1(P, C, lds0, lds1, sv[2], J + 2);
            step1(C, P, lds1, lds0, sv[3], J + 3);
            step1(P, C, lds0, lds1, sv[4], J + 4);
            step1(C, P, lds1, lds0, sv[5], J + 5);
            step1(P, C, lds0, lds1, sv[6], J + 6);
            step1(C, P, lds1, lds0, sv[7], J + 7);
            // C = f_{J+7}, P = f_{J+6}; lds0 = f_{J+7}
        }
        if (ph < NPHASE - 1) {
            float* W0 = (ph & 1) ? GB0 : GA0;
            float* W1 = (ph & 1) ? GB1 : GA1;
            if (inner) {   // interior partition of both levels -> global
                float* c0p = W0 + r * WCELLS;
                float* c1p = W1 + r * WCELLS;
                #pragma unroll
                for (int rr = 0; rr < 4; ++rr) {
                    int wi = (ri0 + li0 + rr) * WW + (rj0 + lj0);
                    st4(c1p + wi, make_float4(C[rr*4+0], C[rr*4+1], C[rr*4+2], C[rr*4+3]));
                    st4(c0p + wi, make_float4(P[rr*4+0], P[rr*4+1], P[rr*4+2], P[rr*4+3]));
                }
            }
            __syncthreads();                           // all interior writes issued+done
            if (tid == 0) {                            // publish: flush L2, set flag
                __builtin_amdgcn_fence(__ATOMIC_RELEASE, "agent");
                __hip_atomic_store(&flags[ph * NBLK + b], 1,
                                   __ATOMIC_RELAXED, __HIP_MEMORY_SCOPE_AGENT);
            }
            if (tid < 9 && tid != 4) {                 // wait on 3x3 neighbors
                int dti = tid / 3 - 1, dtj = tid % 3 - 1;
                int nti = (tile >> 2) + dti, ntj = (tile & 3) + dtj;
                if ((unsigned)nti < 4u && (unsigned)ntj < 4u) {
                    const int* f = &flags[ph * NBLK + (r << 4) + (nti << 2) + ntj];
                    while (__hip_atomic_load(f, __ATOMIC_RELAXED,
                                             __HIP_MEMORY_SCOPE_AGENT) == 0) {}
                }
            }
            __syncthreads();
            __builtin_amdgcn_fence(__ATOMIC_ACQUIRE, "agent");  // invalidate stale L2
            if (active && !inner) {   // ring threads: reload regs + restage LDS
                const float* c0p = W0 + r * WCELLS;
                const float* c1p = W1 + r * WCELLS;
                #pragma unroll
                for (int rr = 0; rr < 4; ++rr) {
                    int wr = ri0 + li0 + rr, wc = rj0 + lj0;
                    float4 vc = make_float4(0,0,0,0), vp = vc;
                    if ((unsigned)wr < WW && (unsigned)wc < WW) {
                        vc = ld4(c1p + wr * WW + wc);
                        vp = ld4(c0p + wr * WW + wc);
                    }
                    C[rr*4+0]=vc.x; C[rr*4+1]=vc.y; C[rr*4+2]=vc.z; C[rr*4+3]=vc.w;
                    P[rr*4+0]=vp.x; P[rr*4+1]=vp.y; P[rr*4+2]=vp.z; P[rr*4+3]=vp.w;
                    st4(&lds0[offC[rr]], vc);
                }
            }
            __syncthreads();   // lds0 fully = f_{J+7} before next phase
        }
    }
}

extern "C" void kernel_launch(void* const* d_in, const int* in_sizes, int n_in,
                              void* d_out, int out_size, void* d_ws, size_t ws_size,
                              hipStream_t stream)
{
    const float* x     = (const float*)d_in[0];
    const float* src   = (const float*)d_in[1];
    const int*   meas  = (const int*)d_in[2];
    const int*   trans = (const int*)d_in[3];
    float* outp = (float*)d_out;

    int*   flags = (int*)d_ws;                          // NPHASE*NBLK ints
    float* GA0 = (float*)((char*)d_ws + 8192);
    float* GA1 = GA0 + (size_t)NCH * WCELLS;
    float* GB0 = GA1 + (size_t)NCH * WCELLS;
    float* GB1 = GB0 + (size_t)NCH * WCELLS;

    hipMemsetAsync(flags, 0, NPHASE * NBLK * sizeof(int), stream);
    hipMemsetAsync(outp, 0, (size_t)out_size * sizeof(float), stream);

    persist_kernel<<<NBLK, NTH, 0, stream>>>(x, src, meas, trans, flags,
                                             GA0, GA1, GB0, GB1, outp);
}

// Round 6
// 87.527 us; speedup vs baseline: 7.3404x; 1.9480x over previous
//
#include <hip/hip_runtime.h>

// Wave forward: 16 channels, 208x208 window/channel, 48 steps, ONE persistent
// kernel. 6 phases x 8 substeps; phase boundaries sync only the 3x3 tile
// neighborhood via agent-scope atomic flags. ALL cross-block data moves via
// relaxed agent-scope atomic load/store (per-access coherent across XCDs) --
// no cache-wide fences. Frame (16-deep rim of interior) is published from
// LDS; halo is pulled straight into LDS; ring threads refill regs from LDS.

#define GN     512
#define NMASK  511
#define NCH    16
#define NT     48
#define NM     128
#define WW     208            // window size
#define WOFF   103            // source offset inside window
#define TI     52             // tile interior
#define TS     8              // substeps per phase
#define NPHASE 6
#define HALO   16             // 2*TS
#define LT     84             // tile width (TI + 2*HALO)
#define LTS    84             // LDS row stride (4-row stride 336 ≡ 16 mod 32 banks: free 2-way)
#define LDSE   (LTS*LT)       // 7056
#define WCELLS (WW*WW)        // 43264
#define NTH    448            // 7 waves
#define NACT   441            // 21x21 threads x 4x4 cells = 84^2
#define NBLK   256
#define FRAME_N 2304          // interior rim cells (52^2 - 20^2)
#define FRAME_A 1664          // rows 16-31,52-67 x cols 16-67
#define HALO_N  4352          // 84^2 - 52^2
#define HALO_TB 2688          // rows 0-15,68-83 x cols 0-83

__device__ __forceinline__ float4 ld4(const float* p) { return *(const float4*)p; }
__device__ __forceinline__ void st4(float* p, float4 v) { *(float4*)p = v; }

__device__ __forceinline__ float kcoef(const float* __restrict__ x, int gi, int gj) {
    float xp;
    if (gi < 55 || gi >= 457 || gj < 55 || gj >= 457)
        xp = 1e-6f;                                   // ABC pad
    else if (gi >= 128 && gi < 384 && gj >= 128 && gj < 384)
        xp = x[(gi - 128) * 256 + (gj - 128)];
    else
        xp = 1.5f;                                    // bg pad
    float t = 0.2f * xp;
    return t * t;
}

__global__ __launch_bounds__(NTH, 1)
void persist_kernel(const float* __restrict__ x,
                    const float* __restrict__ src,
                    const int* __restrict__ meas,
                    const int* __restrict__ trans,
                    int* __restrict__ flags,
                    float* __restrict__ GA0, float* __restrict__ GA1,
                    float* __restrict__ GB0, float* __restrict__ GB1,
                    float* __restrict__ out)
{
    __shared__ float lds0[LDSE];
    __shared__ float lds1[LDSE];
    const int tid  = threadIdx.x;
    const int b    = blockIdx.x;
    const int r    = b >> 4;
    const int tile = b & 15;
    const int ri0  = (tile >> 2) * TI - HALO;
    const int rj0  = (tile &  3) * TI - HALO;

    const bool active = tid < NACT;
    const int ty = tid / 21, tx = tid - 21 * (tid / 21);
    const int li0 = 4 * ty, lj0 = 4 * tx;
    const bool inner = active && tx >= 4 && tx <= 16 && ty >= 4 && ty <= 16;

    // zero BOTH buffers (dead blocks publish zeros from LDS)
    for (int q = tid; q < LDSE / 4; q += NTH) {
        st4(&lds0[q * 4], make_float4(0.f, 0.f, 0.f, 0.f));
        st4(&lds1[q * 4], make_float4(0.f, 0.f, 0.f, 0.f));
    }

    const int trv = trans[r];
    const int ox = (trv >> 9) - WOFF, oy = (trv & NMASK) - WOFF;

    float C[16], P[16], K[16];
    #pragma unroll
    for (int i = 0; i < 16; ++i) { C[i] = 0.f; P[i] = 0.f; K[i] = 0.f; }

    int offT2 = 0, offT1 = 0, offB1 = 0, offB2 = 0;
    int offL[4] = {0,0,0,0}, offR[4] = {0,0,0,0}, offC[4] = {0,0,0,0};
    unsigned smask = 0;
    if (active) {
        #pragma unroll
        for (int rr = 0; rr < 4; ++rr) {
            int wr = ri0 + li0 + rr;
            #pragma unroll
            for (int cc = 0; cc < 4; ++cc) {
                int wc = rj0 + lj0 + cc;
                K[rr*4+cc] = kcoef(x, (ox + wr) & NMASK, (oy + wc) & NMASK);
            }
        }
        int rT2 = li0 - 2 < 0 ? 0 : li0 - 2;
        int rT1 = li0 - 1 < 0 ? 0 : li0 - 1;
        int rB1 = li0 + 4 > LT - 1 ? LT - 1 : li0 + 4;
        int rB2 = li0 + 5 > LT - 1 ? LT - 1 : li0 + 5;
        offT2 = rT2 * LTS + lj0;  offT1 = rT1 * LTS + lj0;
        offB1 = rB1 * LTS + lj0;  offB2 = rB2 * LTS + lj0;
        #pragma unroll
        for (int rr = 0; rr < 4; ++rr) {
            int base = (li0 + rr) * LTS + lj0;
            offC[rr] = base;
            int ol = base - 4;  if (ol < 0) ol = 0;
            int orr = base + 4; if (orr > LDSE - 4) orr = LDSE - 4;
            offL[rr] = ol; offR[rr] = orr;
        }
        int si = (WOFF - ri0) - li0, sj = (WOFF - rj0) - lj0;
        if (si >= 0 && si < 4 && sj >= 0 && sj < 4) smask = 1u << (si * 4 + sj);
    }

    bool mvalid = false; int mlds = 0; float* mout = nullptr;
    if (tid < NM) {
        int mc = meas[tid];
        int mi = ((mc >> 9)    - ox) & NMASK;
        int mj = ((mc & NMASK) - oy) & NMASK;
        int li = mi - ri0, lj = mj - rj0;
        mvalid = (li >= HALO && li < HALO + TI && lj >= HALO && lj < HALO + TI);
        mlds = li * LTS + lj;
        mout = out + (size_t)(r * NM + tid) * NT;
    }

    // support-cone distance from tile's 84^2 region to the source
    int lsi = WOFF - ri0, lsj = WOFF - rj0;
    int di = lsi < 0 ? -lsi : (lsi > LT - 1 ? lsi - (LT - 1) : 0);
    int dj = lsj < 0 ? -lsj : (lsj > LT - 1 ? lsj - (LT - 1) : 0);
    const int sdist = di > dj ? di : dj;

    __syncthreads();

    auto step1 = [&](float (&A)[16], float (&B)[16],
                     const float* rd, float* wb, float sval, int jj) {
        if (active) {
            float t2[4], t1[4], b1a[4], b2a[4];
            float4 v;
            v = ld4(rd + offT2); t2[0]=v.x;  t2[1]=v.y;  t2[2]=v.z;  t2[3]=v.w;
            v = ld4(rd + offT1); t1[0]=v.x;  t1[1]=v.y;  t1[2]=v.z;  t1[3]=v.w;
            v = ld4(rd + offB1); b1a[0]=v.x; b1a[1]=v.y; b1a[2]=v.z; b1a[3]=v.w;
            v = ld4(rd + offB2); b2a[0]=v.x; b2a[1]=v.y; b2a[2]=v.z; b2a[3]=v.w;
            float Lw[4][4], Rw[4][4];
            #pragma unroll
            for (int rr = 0; rr < 4; ++rr) {
                v = ld4(rd + offL[rr]); Lw[rr][0]=v.x; Lw[rr][1]=v.y; Lw[rr][2]=v.z; Lw[rr][3]=v.w;
                v = ld4(rd + offR[rr]); Rw[rr][0]=v.x; Rw[rr][1]=v.y; Rw[rr][2]=v.z; Rw[rr][3]=v.w;
            }
            #pragma unroll
            for (int rr = 0; rr < 4; ++rr) {
                float w[12];
                w[0]=Lw[rr][0]; w[1]=Lw[rr][1]; w[2]=Lw[rr][2];  w[3]=Lw[rr][3];
                w[4]=B[rr*4+0]; w[5]=B[rr*4+1]; w[6]=B[rr*4+2];  w[7]=B[rr*4+3];
                w[8]=Rw[rr][0]; w[9]=Rw[rr][1]; w[10]=Rw[rr][2]; w[11]=Rw[rr][3];
                #pragma unroll
                for (int cc = 0; cc < 4; ++cc) {
                    float vm2 = (rr == 0) ? t2[cc]  : (rr == 1) ? t1[cc]  : B[(rr-2)*4+cc];
                    float vm1 = (rr == 0) ? t1[cc]  : B[(rr-1)*4+cc];
                    float vp1 = (rr == 3) ? b1a[cc] : B[(rr+1)*4+cc];
                    float vp2 = (rr == 3) ? b2a[cc] : (rr == 2) ? b1a[cc] : B[(rr+2)*4+cc];
                    float c0  = w[4+cc];
                    float lap = (16.f * (w[3+cc] + w[5+cc] + vm1 + vp1)
                                 - (w[2+cc] + w[6+cc] + vm2 + vp2)
                                 - 60.f * c0) * (1.f / 12.f);
                    float pn = 2.f * c0 - A[rr*4+cc] + K[rr*4+cc] * lap;
                    if (smask & (1u << (rr*4+cc))) pn += sval;
                    A[rr*4+cc] = pn;
                }
                st4(wb + offC[rr],
                    make_float4(A[rr*4+0], A[rr*4+1], A[rr*4+2], A[rr*4+3]));
            }
        }
        __syncthreads();
        if (mvalid) mout[jj] = wb[mlds];
    };

    for (int ph = 0; ph < NPHASE; ++ph) {
        const int J = ph * TS;
        const bool live = sdist <= 2 * (J + TS) + 4;   // cone: radius 2/step
        if (live) {
            float sv[TS];
            #pragma unroll
            for (int s = 0; s < TS; ++s) sv[s] = 0.09f * src[J + s];
            step1(P, C, lds0, lds1, sv[0], J + 0);
            step1(C, P, lds1, lds0, sv[1], J + 1);
            step1(P, C, lds0, lds1, sv[2], J + 2);
            step1(C, P, lds1, lds0, sv[3], J + 3);
            step1(P, C, lds0, lds1, sv[4], J + 4);
            step1(C, P, lds1, lds0, sv[5], J + 5);
            step1(P, C, lds0, lds1, sv[6], J + 6);
            step1(C, P, lds1, lds0, sv[7], J + 7);
            // lds0 = f_{J+7} (interior valid), lds1 = f_{J+6}
        }
        if (ph < NPHASE - 1) {
            float* W0 = (ph & 1) ? GB0 : GA0;
            float* W1 = (ph & 1) ? GB1 : GA1;
            float* c0p = W0 + r * WCELLS;
            float* c1p = W1 + r * WCELLS;
            // publish frame (coalesced, from LDS; zeros if block still dead)
            for (int q = tid; q < FRAME_N; q += NTH) {
                int row, col;
                if (q < FRAME_A) {
                    int rA = q / 52;
                    row = 16 + (rA < 16 ? rA : rA + 20);
                    col = 16 + (q - rA * 52);
                } else {
                    int q2 = q - FRAME_A;
                    int rB = q2 / 32;
                    int c  = q2 - rB * 32;
                    row = 32 + rB;
                    col = 16 + (c < 16 ? c : c + 20);
                }
                int gw = (ri0 + row) * WW + (rj0 + col);
                int l  = row * LTS + col;
                __hip_atomic_store(&c1p[gw], lds0[l], __ATOMIC_RELAXED, __HIP_MEMORY_SCOPE_AGENT);
                __hip_atomic_store(&c0p[gw], lds1[l], __ATOMIC_RELAXED, __HIP_MEMORY_SCOPE_AGENT);
            }
            asm volatile("s_waitcnt vmcnt(0)" ::: "memory");  // my stores at coherence point
            __syncthreads();                                   // whole block done
            if (tid == 0)
                __hip_atomic_store(&flags[ph * NBLK + b], 1,
                                   __ATOMIC_RELAXED, __HIP_MEMORY_SCOPE_AGENT);
            if (tid < 9 && tid != 4) {                         // wait 3x3 neighbors
                int dti = tid / 3 - 1, dtj = tid % 3 - 1;
                int nti = (tile >> 2) + dti, ntj = (tile & 3) + dtj;
                if ((unsigned)nti < 4u && (unsigned)ntj < 4u) {
                    int* f = &flags[ph * NBLK + (r << 4) + (nti << 2) + ntj];
                    while (__hip_atomic_load(f, __ATOMIC_RELAXED,
                                             __HIP_MEMORY_SCOPE_AGENT) == 0) {}
                }
            }
            __syncthreads();
            // pull halo (coalesced into LDS: completes lds0/lds1 to full tiles)
            for (int q = tid; q < HALO_N; q += NTH) {
                int row, col;
                if (q < HALO_TB) {
                    int rT = q / 84;
                    row = rT < 16 ? rT : rT + 52;
                    col = q - rT * 84;
                } else {
                    int q2 = q - HALO_TB;
                    int rM = q2 / 32;
                    int c  = q2 - rM * 32;
                    row = 16 + rM;
                    col = c < 16 ? c : c + 52;
                }
                int wr = ri0 + row, wc = rj0 + col;
                float v1 = 0.f, v0 = 0.f;
                if ((unsigned)wr < WW && (unsigned)wc < WW) {
                    int gw = wr * WW + wc;
                    v1 = __hip_atomic_load(&c1p[gw], __ATOMIC_RELAXED, __HIP_MEMORY_SCOPE_AGENT);
                    v0 = __hip_atomic_load(&c0p[gw], __ATOMIC_RELAXED, __HIP_MEMORY_SCOPE_AGENT);
                }
                int l = row * LTS + col;
                lds0[l] = v1;
                lds1[l] = v0;
            }
            __syncthreads();
            // ring threads refill registers from completed LDS
            if (active && !inner) {
                #pragma unroll
                for (int rr = 0; rr < 4; ++rr) {
                    float4 vc = ld4(&lds0[offC[rr]]);
                    float4 vp = ld4(&lds1[offC[rr]]);
                    C[rr*4+0]=vc.x; C[rr*4+1]=vc.y; C[rr*4+2]=vc.z; C[rr*4+3]=vc.w;
                    P[rr*4+0]=vp.x; P[rr*4+1]=vp.y; P[rr*4+2]=vp.z; P[rr*4+3]=vp.w;
                }
            }
        }
    }
}

extern "C" void kernel_launch(void* const* d_in, const int* in_sizes, int n_in,
                              void* d_out, int out_size, void* d_ws, size_t ws_size,
                              hipStream_t stream)
{
    const float* x     = (const float*)d_in[0];
    const float* src   = (const float*)d_in[1];
    const int*   meas  = (const int*)d_in[2];
    const int*   trans = (const int*)d_in[3];
    float* outp = (float*)d_out;

    int*   flags = (int*)d_ws;                          // NPHASE*NBLK ints
    float* GA0 = (float*)((char*)d_ws + 8192);
    float* GA1 = GA0 + (size_t)NCH * WCELLS;
    float* GB0 = GA1 + (size_t)NCH * WCELLS;
    float* GB1 = GB0 + (size_t)NCH * WCELLS;

    hipMemsetAsync(flags, 0, NPHASE * NBLK * sizeof(int), stream);
    hipMemsetAsync(outp, 0, (size_t)out_size * sizeof(float), stream);

    persist_kernel<<<NBLK, NTH, 0, stream>>>(x, src, meas, trans, flags,
                                             GA0, GA1, GB0, GB1, outp);
}